// Round 6
// baseline (283.197 us; speedup 1.0000x reference)
//
#include <hip/hip_runtime.h>
#include <stdint.h>

#pragma clang fp contract(off)

#define BB 16
#define NN 25200
#define ROW 85
#define NCLS 80
#define TK 2048
#define SORTN 4096
#define NBIN 4096
#define MAXDET 1000
#define CONF 0.25f
#define IOUT 0.45f
#define SROWS 64
#define STH 0x3E800000u

typedef float fvec4 __attribute__((ext_vector_type(4)));

#define AS1 __attribute__((address_space(1)))
#define AS3 __attribute__((address_space(3)))

// ---------------- K1: coalesced LDS staging + scores + argmax class ----------------
// No histogram, no atomics, no memset dependency.
__global__ __launch_bounds__(128) void score_kernel(const float* __restrict__ pred,
                                                    float* __restrict__ scores,
                                                    uint8_t* __restrict__ cls) {
  __shared__ __align__(16) float srow[SROWS * ROW];  // 21760 B
  const int tile = blockIdx.x;
  const int b = blockIdx.y;
  const int tid = threadIdx.x;
  const int lane = tid & 63;
  const int row0 = tile * SROWS;
  int nrows = NN - row0;
  if (nrows > SROWS) nrows = SROWS;
  const char* gsrc = (const char*)(pred + ((size_t)b * NN + row0) * ROW);
  const int nbytes = nrows * ROW * 4;
  for (int off = tid * 16; off < nbytes; off += 128 * 16) {
    __builtin_amdgcn_global_load_lds((AS1 void*)(gsrc + off),
                                     (AS3 void*)((char*)srow + (off - lane * 16)),
                                     16, 0, 0);
  }
  __builtin_amdgcn_s_waitcnt(0);
  __syncthreads();
  if (tid < nrows) {
    const int n = row0 + tid;
    const float* r = srow + tid * ROW;   // stride 85 dwords -> 2-way bank alias (free)
    float obj = r[4];
    float best = r[5];
    int bid = 0;
#pragma unroll
    for (int c = 1; c < NCLS; ++c) {
      float p = r[5 + c];
      if (p > best) { best = p; bid = c; }   // strict > keeps first max (tie rule)
    }
    float score = obj * best;
    bool valid = (obj > CONF) && (score > CONF);
    scores[(size_t)b * NN + n] = valid ? score : 0.0f;
    cls[(size_t)b * NN + n] = (uint8_t)bid;
  }
}

// ---------------- K2: per-batch mega — LDS hist + shfl suffix-scan + scatter +
//                  rank-emit + per-class compact + register NMS + output ----------------
__global__ __launch_bounds__(1024) void mega_kernel(const float* __restrict__ pred,
                                                    const float* __restrict__ scores,
                                                    const uint8_t* __restrict__ cls,
                                                    float* __restrict__ out) {
  const int b = blockIdx.x;
  const int t = threadIdx.x;
  const int w = t >> 6;
  const int lane = t & 63;
  __shared__ unsigned int hist[NBIN];          // 16 KB counts (preserved)
  __shared__ unsigned int soff[NBIN];          // 16 KB suffix offsets -> scatter cursors
  __shared__ unsigned long long skey[SORTN];   // 32 KB
  __shared__ float sx1[TK], sy1[TK], sx2[TK], sy2[TK];  // 32 KB boxes (xyxy)
  __shared__ float stop[TK];                   // 8 KB scores
  __shared__ unsigned short scls[TK];          // 4 KB class ids (0xFFFF = pad)
  __shared__ unsigned short cgrpL[TK];         // 4 KB per-class lists
  __shared__ unsigned char skp[TK];            // 2 KB keep flags
  __shared__ int ccnt[NCLS];
  __shared__ int coffs[NCLS + 1];
  __shared__ int swsum[16];
  __shared__ int sP, sTot, sfound;

  const unsigned int* su = (const unsigned int*)(scores + (size_t)b * NN);

  // ---- phase 0: zero hist ----
  for (int i = t; i < NBIN; i += 1024) hist[i] = 0u;
  if (t == 0) sfound = 0;
  __syncthreads();

  // ---- phase 1: build histogram from scores (coalesced, ~25 iters) ----
  for (int n = t; n < NN; n += 1024) {
    unsigned int u = su[n];
    if (u > STH) {
      unsigned int bin = (u - (STH + 1u)) >> 12;
      if (bin > NBIN - 1) bin = NBIN - 1;
      atomicAdd(&hist[bin], 1u);
    }
  }
  __syncthreads();

  // ---- phase 2: suffix scan over descending bins (shfl, 3 barriers) + pivot ----
  int loc[4];
  int ssum = 0;
#pragma unroll
  for (int k = 0; k < 4; ++k) {
    loc[k] = (int)hist[NBIN - 1 - (4 * t + k)];
    ssum += loc[k];
  }
  int v = ssum;
  for (int o = 1; o < 64; o <<= 1) { int uu = __shfl_up(v, o); if (lane >= o) v += uu; }
  if (lane == 63) swsum[w] = v;
  __syncthreads();
  if (w == 0) {
    int x = (lane < 16) ? swsum[lane] : 0;
    for (int o = 1; o < 16; o <<= 1) { int uu = __shfl_up(x, o); if (lane >= o) x += uu; }
    if (lane < 16) swsum[lane] = x;   // inclusive wave sums
  }
  __syncthreads();
  const int total = swsum[15];
  int run = (w ? swsum[w - 1] : 0) + (v - ssum);  // exclusive sum over higher bins
#pragma unroll
  for (int k = 0; k < 4; ++k) {
    int bin = NBIN - 1 - (4 * t + k);
    soff[bin] = (unsigned int)run;
    if (run < TK && run + loc[k] >= TK) {   // unique bin satisfies this
      sP = bin; sTot = run + loc[k]; sfound = 1;
    }
    run += loc[k];
  }
  __syncthreads();
  if (t == 0 && !sfound) { sP = 0; sTot = total; }  // total < TK (never with this data)
  __syncthreads();
  const int P = sP;
  const int tot = sTot;
  const int used = tot < SORTN ? tot : SORTN;
  const int npos = tot < TK ? tot : TK;

  // ---- phase 3: scatter bin>=P to LDS segments (cursor = soff itself) + pad-init ----
  for (int n = t; n < NN; n += 1024) {
    unsigned int u = su[n];              // L2-resident re-read
    if (u > STH) {
      unsigned int bin = (u - (STH + 1u)) >> 12;
      if (bin > NBIN - 1) bin = NBIN - 1;
      if ((int)bin >= P) {
        unsigned int pos = atomicAdd(&soff[bin], 1u);
        if (pos < SORTN)
          skey[pos] = ((unsigned long long)u << 32) | (unsigned int)(~n);
      }
    }
  }
  for (int i = npos + t; i < TK; i += 1024) {
    sx1[i] = 0.f; sy1[i] = 0.f; sx2[i] = 0.f; sy2[i] = 0.f;
    stop[i] = 0.f;
    scls[i] = (unsigned short)0xFFFFu;
    skp[i] = 0;
  }
  __syncthreads();

  // ---- phase 4: rank-by-count + direct emit (thread per candidate) ----
  // soff[bin] advanced by exactly hist[bin] for bins >= P  =>  base = soff - hist.
  // rank within segment is a bijection (keys unique) -> every q < npos filled once.
  for (int p = t; p < used; p += 1024) {
    unsigned long long k = skey[p];
    unsigned int u = (unsigned int)(k >> 32);
    unsigned int bin = (u - (STH + 1u)) >> 12;
    if (bin > NBIN - 1) bin = NBIN - 1;
    int cnt = (int)hist[bin];
    int base = (int)soff[bin] - cnt;
    if (base + cnt > used) cnt = used - base;   // safety
    int rank = 0;
    for (int j = 0; j < cnt; ++j) rank += (skey[base + j] > k) ? 1 : 0;  // LDS, avg ~6
    int q = base + rank;
    if (q < npos) {
      int idx = (int)(~(unsigned int)k);
      stop[q] = __uint_as_float(u);
      scls[q] = (unsigned short)cls[(size_t)b * NN + idx];
      skp[q] = 1;
      const float* rowp = pred + ((size_t)b * NN + idx) * ROW;
      float cx = rowp[0], cy = rowp[1], w2 = rowp[2], h2 = rowp[3];
      float hw = w2 * 0.5f, hh = h2 * 0.5f;
      sx1[q] = cx - hw; sy1[q] = cy - hh; sx2[q] = cx + hw; sy2[q] = cy + hh;
    }
  }
  __syncthreads();

  // ---- phase 5: stable per-class compaction (register-cached scls) ----
  int myv[32];
#pragma unroll
  for (int ch = 0; ch < 32; ++ch) myv[ch] = (int)scls[ch * 64 + lane];
#pragma unroll
  for (int k = 0; k < 5; ++k) {
    int c = w + 16 * k;
    int cnt = 0;
#pragma unroll
    for (int ch = 0; ch < 32; ++ch)
      cnt += (int)__popcll(__ballot(myv[ch] == c));
    if (lane == 0) ccnt[c] = cnt;
  }
  __syncthreads();
  if (t == 0) {
    int r2 = 0;
    for (int c = 0; c < NCLS; ++c) { coffs[c] = r2; r2 += ccnt[c]; }
    coffs[NCLS] = r2;
  }
  __syncthreads();
#pragma unroll
  for (int k = 0; k < 5; ++k) {
    int c = w + 16 * k;
    int run2 = coffs[c];
#pragma unroll
    for (int ch = 0; ch < 32; ++ch) {
      bool match = (myv[ch] == c);
      unsigned long long bal = __ballot(match);
      int r3 = (int)__popcll(bal & ((1ull << lane) - 1ull));
      if (match) cgrpL[run2 + r3] = (unsigned short)(ch * 64 + lane);
      run2 += (int)__popcll(bal);
    }
  }
  __syncthreads();

  // ---- phase 6: per-class greedy NMS, register-resident ----
  for (int k = 0; k < 5; ++k) {
    int c = w + 16 * k;
    int start = coffs[c];
    int m = coffs[c + 1] - start;
    if (m <= 0) continue;
    int nq = (m + 63) >> 6;
    unsigned int km = 0;
    for (int q = 0; q < nq; ++q)
      if (lane + (q << 6) < m) km |= (1u << q);
    float b0x1 = 0.f, b0y1 = 0.f, b0x2 = 0.f, b0y2 = 0.f;
    if (lane < m) {
      int e0 = cgrpL[start + lane];
      b0x1 = sx1[e0]; b0y1 = sy1[e0]; b0x2 = sx2[e0]; b0y2 = sy2[e0];
    }
    for (int i = 0; i < m; ++i) {
      int q = i >> 6;
      unsigned int kmi = __shfl(km, i & 63);
      if (!((kmi >> q) & 1u)) continue;   // suppressed pivot: uniform skip
      float ax1, ay1, ax2, ay2;
      if (q == 0) {
        ax1 = __shfl(b0x1, i); ay1 = __shfl(b0y1, i);
        ax2 = __shfl(b0x2, i); ay2 = __shfl(b0y2, i);
      } else {
        int ei = cgrpL[start + i];
        ax1 = sx1[ei]; ay1 = sy1[ei]; ax2 = sx2[ei]; ay2 = sy2[ei];
      }
      float aarea = (ax2 - ax1) * (ay2 - ay1);
      if ((km & 1u) && lane > i) {        // chunk 0: j = lane
        float ltx = fmaxf(ax1, b0x1), lty = fmaxf(ay1, b0y1);
        float rbx = fminf(ax2, b0x2), rby = fminf(ay2, b0y2);
        float iw = fmaxf(rbx - ltx, 0.0f);
        float ih = fmaxf(rby - lty, 0.0f);
        float inter = iw * ih;
        float barea = (b0x2 - b0x1) * (b0y2 - b0y1);
        float iou = inter / (aarea + barea - inter + 1e-7f);
        if (iou > IOUT) km &= ~1u;
      }
      for (int q2 = 1; q2 < nq; ++q2) {   // rare chunks (m > 64)
        int j = lane + (q2 << 6);
        if (((km >> q2) & 1u) && j > i && j < m) {
          int ej = cgrpL[start + j];
          float jx1 = sx1[ej], jy1 = sy1[ej], jx2 = sx2[ej], jy2 = sy2[ej];
          float ltx = fmaxf(ax1, jx1), lty = fmaxf(ay1, jy1);
          float rbx = fminf(ax2, jx2), rby = fminf(ay2, jy2);
          float iw = fmaxf(rbx - ltx, 0.0f);
          float ih = fmaxf(rby - lty, 0.0f);
          float inter = iw * ih;
          float barea = (jx2 - jx1) * (jy2 - jy1);
          float iou = inter / (aarea + barea - inter + 1e-7f);
          if (iou > IOUT) km &= ~(1u << q2);
        }
      }
    }
    for (int q = 0; q < nq; ++q) {
      int j = lane + (q << 6);
      if (j < m) skp[cgrpL[start + j]] = (unsigned char)((km >> q) & 1u);
    }
  }
  __syncthreads();

  // ---- phase 7: output compaction (shfl-based scan) ----
  int kp0 = (int)skp[2 * t];
  int kp1 = (int)skp[2 * t + 1];
  int cnt2 = kp0 + kp1;
  int v2 = cnt2;
  for (int o = 1; o < 64; o <<= 1) { int u2 = __shfl_up(v2, o); if (lane >= o) v2 += u2; }
  if (lane == 63) swsum[w] = v2;
  __syncthreads();
  if (w == 0) {
    int x = (lane < 16) ? swsum[lane] : 0;
    for (int o = 1; o < 16; o <<= 1) { int u2 = __shfl_up(x, o); if (lane >= o) x += u2; }
    if (lane < 16) swsum[lane] = x;   // inclusive wave sums
  }
  __syncthreads();
  int r4 = (w ? swsum[w - 1] : 0) + v2 - cnt2;
  int K = swsum[15];
#pragma unroll
  for (int k = 0; k < 2; ++k) {
    int kp = (k == 0) ? kp0 : kp1;
    if (kp) {
      if (r4 < MAXDET) {
        int j = 2 * t + k;
        float* o = out + ((size_t)b * MAXDET + r4) * 6;
        o[0] = sx1[j]; o[1] = sy1[j]; o[2] = sx2[j]; o[3] = sy2[j];
        o[4] = stop[j];
        o[5] = (float)scls[j];
      }
      ++r4;
    }
  }
  int Kc = K < MAXDET ? K : MAXDET;
  for (int r2 = Kc + t; r2 < MAXDET; r2 += 1024) {
    float* o = out + ((size_t)b * MAXDET + r2) * 6;
    o[0] = 0.0f; o[1] = 0.0f; o[2] = 0.0f; o[3] = 0.0f; o[4] = 0.0f; o[5] = -1.0f;
  }
}

extern "C" void kernel_launch(void* const* d_in, const int* in_sizes, int n_in,
                              void* d_out, int out_size, void* d_ws, size_t ws_size,
                              hipStream_t stream) {
  const float* pred = (const float*)d_in[0];
  float* out = (float*)d_out;

  char* ws = (char*)d_ws;
  size_t off = 0;
  float*   scores = (float*)(ws + off);   off += (size_t)BB * NN * 4;
  uint8_t* cls    = (uint8_t*)(ws + off); off += (size_t)BB * NN;
  (void)ws_size; (void)in_sizes; (void)n_in; (void)out_size;

  score_kernel<<<dim3((NN + SROWS - 1) / SROWS, BB), 128, 0, stream>>>(pred, scores, cls);
  mega_kernel<<<BB, 1024, 0, stream>>>(pred, scores, cls, out);
}

// Round 8
// 260.477 us; speedup vs baseline: 1.0872x; 1.0872x over previous
//
#include <hip/hip_runtime.h>
#include <stdint.h>

#pragma clang fp contract(off)

#define BB 16
#define NN 25200
#define ROW 85
#define NCLS 80
#define TK 2048
#define SORTN 4096
#define NBIN 4096
#define MAXDET 1000
#define CONF 0.25f
#define IOUT 0.45f
#define SROWS 64
#define STH 0x3E800000u

typedef float fvec4 __attribute__((ext_vector_type(4)));

#define AS1 __attribute__((address_space(1)))
#define AS3 __attribute__((address_space(3)))

// ---------------- K1: coalesced LDS staging + scores + argmax + global histogram ----------------
__global__ __launch_bounds__(128) void score_kernel(const float* __restrict__ pred,
                                                    float* __restrict__ scores,
                                                    uint8_t* __restrict__ cls,
                                                    unsigned int* __restrict__ hist) {
  __shared__ __align__(16) float srow[SROWS * ROW];  // 21760 B
  const int tile = blockIdx.x;
  const int b = blockIdx.y;
  const int tid = threadIdx.x;
  const int lane = tid & 63;
  const int row0 = tile * SROWS;
  int nrows = NN - row0;
  if (nrows > SROWS) nrows = SROWS;
  const char* gsrc = (const char*)(pred + ((size_t)b * NN + row0) * ROW);
  const int nbytes = nrows * ROW * 4;
  for (int off = tid * 16; off < nbytes; off += 128 * 16) {
    __builtin_amdgcn_global_load_lds((AS1 void*)(gsrc + off),
                                     (AS3 void*)((char*)srow + (off - lane * 16)),
                                     16, 0, 0);
  }
  __builtin_amdgcn_s_waitcnt(0);
  __syncthreads();
  if (tid < nrows) {
    const int n = row0 + tid;
    const float* r = srow + tid * ROW;   // stride 85 dwords -> 2-way bank alias (free)
    float obj = r[4];
    float best = r[5];
    int bid = 0;
#pragma unroll
    for (int c = 1; c < NCLS; ++c) {
      float p = r[5 + c];
      if (p > best) { best = p; bid = c; }   // strict > keeps first max (tie rule)
    }
    float score = obj * best;
    bool valid = (obj > CONF) && (score > CONF);
    float sout = valid ? score : 0.0f;
    scores[(size_t)b * NN + n] = sout;
    cls[(size_t)b * NN + n] = (uint8_t)bid;
    if (valid) {
      unsigned int u = __float_as_uint(sout);        // in (0x3E800000, 0x3F800000)
      unsigned int bin = (u - (STH + 1u)) >> 12;
      if (bin > NBIN - 1) bin = NBIN - 1;
      atomicAdd(&hist[(size_t)b * NBIN + bin], 1u);
    }
  }
}

// ---------------- K2: per-batch suffix scan of hist -> gsoff, pivot P, total; zero gcnt ----------------
__global__ __launch_bounds__(256) void scan_kernel(const unsigned int* __restrict__ hist,
                                                   unsigned int* __restrict__ gsoff,
                                                   unsigned int* __restrict__ gcnt,
                                                   int* __restrict__ gP,
                                                   int* __restrict__ gtot) {
  const int b = blockIdx.x;
  const int t = threadIdx.x;
  const int w = t >> 6, lane = t & 63;
  for (int i = t; i < NBIN; i += 256) gcnt[(size_t)b * NBIN + i] = 0u;  // for K3
  const unsigned int* h = hist + (size_t)b * NBIN;
  unsigned int loc[16];
  int ssum = 0;
#pragma unroll
  for (int k = 0; k < 16; ++k) {
    loc[k] = h[NBIN - 1 - (16 * t + k)];   // descending bins
    ssum += (int)loc[k];
  }
  // wave-level inclusive scan of per-thread sums
  int v = ssum;
  for (int o = 1; o < 64; o <<= 1) { int u = __shfl_up(v, o); if (lane >= o) v += u; }
  __shared__ int sw[4];
  __shared__ int sfound;
  if (t == 0) sfound = 0;
  if (lane == 63) sw[w] = v;
  __syncthreads();
  int wbase = 0;
  for (int i = 0; i < w; ++i) wbase += sw[i];
  const int total = sw[0] + sw[1] + sw[2] + sw[3];
  int run = wbase + v - ssum;   // exclusive suffix-sum at this thread's first bin
#pragma unroll
  for (int k = 0; k < 16; ++k) {
    int bin = NBIN - 1 - (16 * t + k);
    gsoff[(size_t)b * NBIN + bin] = (unsigned int)run;
    int c = (int)loc[k];
    if (run < TK && run + c >= TK) {   // unique bin satisfies this
      gP[b] = bin;
      gtot[b] = run + c;
      sfound = 1;
    }
    run += c;
  }
  __syncthreads();
  if (t == 0 && !sfound) { gP[b] = 0; gtot[b] = total; }  // < TK valid (never here)
}

// ---------------- K3: multi-block scatter to exact bin segments (global atomics) ----------------
__global__ __launch_bounds__(1024) void scatter_kernel(const float* __restrict__ scores,
                                                       const unsigned int* __restrict__ gsoff,
                                                       const int* __restrict__ gP,
                                                       unsigned int* __restrict__ gcnt,
                                                       unsigned long long* __restrict__ gskey) {
  const int b = blockIdx.y;
  const int n = blockIdx.x * 1024 + threadIdx.x;
  if (n >= NN) return;
  const unsigned int P = (unsigned int)gP[b];
  unsigned int u = __float_as_uint(scores[(size_t)b * NN + n]);
  if (u > STH) {
    unsigned int bin = (u - (STH + 1u)) >> 12;
    if (bin > NBIN - 1) bin = NBIN - 1;
    if (bin >= P) {
      unsigned int pos = gsoff[(size_t)b * NBIN + bin] +
                         atomicAdd(&gcnt[(size_t)b * NBIN + bin], 1u);
      if (pos < SORTN)
        gskey[(size_t)b * SORTN + pos] = ((unsigned long long)u << 32) | (unsigned int)(~n);
    }
  }
}

// ---------------- K4: wide rank-by-count emit, one thread per scatter position ----------------
// FIX vs R7: grid.x = SORTN/1024 = 4 (was 2). Scatter fills positions [0, tot) and tot can
// exceed TK; a pivot-bin key stored at position >= TK can still have final rank < TK, so ALL
// positions < used must be ranked. Grid-stride loops make coverage config-independent.
__global__ __launch_bounds__(1024) void emit_kernel(const float* __restrict__ pred,
                                                    const uint8_t* __restrict__ cls,
                                                    const unsigned int* __restrict__ gsoff,
                                                    const unsigned int* __restrict__ gcnt,
                                                    const unsigned long long* __restrict__ gskey,
                                                    const int* __restrict__ gtot,
                                                    float* __restrict__ gtops,
                                                    fvec4* __restrict__ gbox,
                                                    int* __restrict__ gcls) {
  const int b = blockIdx.y;
  const int stride = gridDim.x * 1024;
  const int tot = gtot[b];
  const int used = tot < SORTN ? tot : SORTN;
  const int npos = tot < TK ? tot : TK;
  // pad job: fill [npos, TK) (no-op when tot >= TK)
  for (int ip = npos + blockIdx.x * 1024 + threadIdx.x; ip < TK; ip += stride) {
    gtops[(size_t)b * TK + ip] = 0.0f;
    gcls[(size_t)b * TK + ip] = 0xFFFF;
    fvec4 z; z[0] = 0.f; z[1] = 0.f; z[2] = 0.f; z[3] = 0.f;
    gbox[(size_t)b * TK + ip] = z;
  }
  for (int pp = blockIdx.x * 1024 + threadIdx.x; pp < used; pp += stride) {
    unsigned long long k = gskey[(size_t)b * SORTN + pp];
    unsigned int u = (unsigned int)(k >> 32);
    unsigned int bin = (u - (STH + 1u)) >> 12;
    if (bin > NBIN - 1) bin = NBIN - 1;
    int base = (int)gsoff[(size_t)b * NBIN + bin];
    int cnt = (int)gcnt[(size_t)b * NBIN + bin];
    if (base + cnt > used) cnt = used - base;   // safety
    const unsigned long long* seg = gskey + (size_t)b * SORTN + base;
    int rank = 0;
    for (int j = 0; j < cnt; ++j) rank += (seg[j] > k) ? 1 : 0;   // L2-resident, avg ~6
    int q = base + rank;                 // bijection over the segment (keys unique)
    if (q < npos) {
      int idx = (int)(~(unsigned int)k);
      gtops[(size_t)b * TK + q] = __uint_as_float(u);
      gcls[(size_t)b * TK + q] = (int)cls[(size_t)b * NN + idx];
      const float* rowp = pred + ((size_t)b * NN + idx) * ROW;
      float cx = rowp[0], cy = rowp[1], w2 = rowp[2], h2 = rowp[3];
      float hw = w2 * 0.5f, hh = h2 * 0.5f;
      fvec4 bb4;
      bb4[0] = cx - hw; bb4[1] = cy - hh; bb4[2] = cx + hw; bb4[3] = cy + hh;
      gbox[(size_t)b * TK + q] = bb4;
    }
  }
}

// ---------------- K5: greedy NMS, one wave per (batch, class) — R0-proven structure ----------------
__global__ __launch_bounds__(64) void nms_kernel(const float* __restrict__ gtops,
                                                 const fvec4* __restrict__ gbox,
                                                 const int* __restrict__ gcls,
                                                 int* __restrict__ keep) {
  const int c = blockIdx.x;
  const int b = blockIdx.y;
  const int lane = threadIdx.x;
  __shared__ float sx1[TK], sy1[TK], sx2[TK], sy2[TK];
  __shared__ unsigned short spos[TK];
  __shared__ unsigned char skp[TK];

  int m = 0;
  for (int base = 0; base < TK; base += 64) {
    int j = base + lane;
    bool match = (gcls[(size_t)b * TK + j] == c);
    unsigned long long bal = __ballot(match);
    int mp = m + __popcll(bal & ((1ull << lane) - 1ull));
    if (match) {
      spos[mp] = (unsigned short)j;
      fvec4 bx = gbox[(size_t)b * TK + j];
      sx1[mp] = bx[0]; sy1[mp] = bx[1]; sx2[mp] = bx[2]; sy2[mp] = bx[3];
      skp[mp] = (gtops[(size_t)b * TK + j] > 0.0f) ? 1 : 0;
    }
    m += (int)__popcll(bal);
  }
  __syncthreads();

  for (int i = 0; i < m; ++i) {
    __syncthreads();
    if (!skp[i]) continue;  // uniform across the wave
    float ax1 = sx1[i], ay1 = sy1[i], ax2 = sx2[i], ay2 = sy2[i];
    float aarea = (ax2 - ax1) * (ay2 - ay1);
    for (int j = i + 1 + lane; j < m; j += 64) {
      float bx1 = sx1[j], by1 = sy1[j], bx2 = sx2[j], by2 = sy2[j];
      float ltx = fmaxf(ax1, bx1), lty = fmaxf(ay1, by1);
      float rbx = fminf(ax2, bx2), rby = fminf(ay2, by2);
      float iw = fmaxf(rbx - ltx, 0.0f);
      float ih = fmaxf(rby - lty, 0.0f);
      float inter = iw * ih;
      float barea = (bx2 - bx1) * (by2 - by1);
      float iou = inter / (aarea + barea - inter + 1e-7f);
      if (iou > IOUT) skp[j] = 0;
    }
  }
  __syncthreads();

  for (int i = lane; i < m; i += 64) {
    keep[(size_t)b * TK + spos[i]] = skp[i];
  }
}

// ---------------- K6: compact first 1000 kept + padding — R0-proven structure ----------------
__global__ __launch_bounds__(256) void out_kernel(const float* __restrict__ gtops,
                                                  const fvec4* __restrict__ gbox,
                                                  const int* __restrict__ gcls,
                                                  const int* __restrict__ keep,
                                                  const int* __restrict__ gtot,
                                                  float* __restrict__ out) {
  int b = blockIdx.x;
  int t = threadIdx.x;
  __shared__ int scnt[256];
  int npos = gtot[b];
  if (npos > TK) npos = TK;
  const int CH = TK / 256;  // 8
  int base = t * CH;
  int kp[CH];
  int cnt = 0;
  for (int k = 0; k < CH; ++k) {
    int j = base + k;
    kp[k] = (j < npos) ? keep[(size_t)b * TK + j] : 0;
    cnt += kp[k];
  }
  scnt[t] = cnt;
  __syncthreads();
  for (int off = 1; off < 256; off <<= 1) {
    int v = (t >= off) ? scnt[t - off] : 0;
    __syncthreads();
    scnt[t] += v;
    __syncthreads();
  }
  int r = scnt[t] - cnt;
  int K = scnt[255];
  for (int k = 0; k < CH; ++k) {
    if (kp[k]) {
      if (r < MAXDET) {
        int j = base + k;
        float* o = out + ((size_t)b * MAXDET + r) * 6;
        fvec4 bx = gbox[(size_t)b * TK + j];
        o[0] = bx[0]; o[1] = bx[1]; o[2] = bx[2]; o[3] = bx[3];
        o[4] = gtops[(size_t)b * TK + j];
        o[5] = (float)gcls[(size_t)b * TK + j];
      }
      ++r;
    }
  }
  int Kc = K < MAXDET ? K : MAXDET;
  for (int r2 = Kc + t; r2 < MAXDET; r2 += 256) {
    float* o = out + ((size_t)b * MAXDET + r2) * 6;
    o[0] = 0.0f; o[1] = 0.0f; o[2] = 0.0f; o[3] = 0.0f; o[4] = 0.0f; o[5] = -1.0f;
  }
}

extern "C" void kernel_launch(void* const* d_in, const int* in_sizes, int n_in,
                              void* d_out, int out_size, void* d_ws, size_t ws_size,
                              hipStream_t stream) {
  const float* pred = (const float*)d_in[0];
  float* out = (float*)d_out;

  char* ws = (char*)d_ws;
  size_t off = 0;
  float*              scores = (float*)(ws + off);              off += (size_t)BB * NN * 4;
  uint8_t*            cls    = (uint8_t*)(ws + off);            off += (size_t)BB * NN;
  off = (off + 255) & ~(size_t)255;
  unsigned int*       hist   = (unsigned int*)(ws + off);       off += (size_t)BB * NBIN * 4;
  unsigned int*       gcnt   = (unsigned int*)(ws + off);       off += (size_t)BB * NBIN * 4;
  unsigned int*       gsoff  = (unsigned int*)(ws + off);       off += (size_t)BB * NBIN * 4;
  unsigned long long* gskey  = (unsigned long long*)(ws + off); off += (size_t)BB * SORTN * 8;
  float*              gtops  = (float*)(ws + off);              off += (size_t)BB * TK * 4;
  fvec4*              gbox   = (fvec4*)(ws + off);              off += (size_t)BB * TK * 16;
  int*                gcls   = (int*)(ws + off);                off += (size_t)BB * TK * 4;
  int*                keep   = (int*)(ws + off);                off += (size_t)BB * TK * 4;
  int*                gP     = (int*)(ws + off);                off += (size_t)BB * 4;
  int*                gtot   = (int*)(ws + off);                off += (size_t)BB * 4;
  (void)ws_size; (void)in_sizes; (void)n_in; (void)out_size;

  hipMemsetAsync(hist, 0, (size_t)BB * NBIN * 4, stream);
  score_kernel<<<dim3((NN + SROWS - 1) / SROWS, BB), 128, 0, stream>>>(pred, scores, cls, hist);
  scan_kernel<<<BB, 256, 0, stream>>>(hist, gsoff, gcnt, gP, gtot);
  scatter_kernel<<<dim3((NN + 1023) / 1024, BB), 1024, 0, stream>>>(scores, gsoff, gP, gcnt, gskey);
  emit_kernel<<<dim3(SORTN / 1024, BB), 1024, 0, stream>>>(pred, cls, gsoff, gcnt, gskey, gtot,
                                                           gtops, gbox, gcls);
  nms_kernel<<<dim3(NCLS, BB), 64, 0, stream>>>(gtops, gbox, gcls, keep);
  out_kernel<<<BB, 256, 0, stream>>>(gtops, gbox, gcls, keep, gtot, out);
}

// Round 9
// 247.305 us; speedup vs baseline: 1.1451x; 1.0533x over previous
//
#include <hip/hip_runtime.h>
#include <stdint.h>

#pragma clang fp contract(off)

#define BB 16
#define NN 25200
#define ROW 85
#define NCLS 80
#define TK 2048
#define SORTN 4096
#define NBIN 4096
#define MAXDET 1000
#define CONF 0.25f
#define IOUT 0.45f
#define SROWS 64
#define STH 0x3E800000u
#define MCAP 256

typedef float fvec4 __attribute__((ext_vector_type(4)));

#define AS1 __attribute__((address_space(1)))
#define AS3 __attribute__((address_space(3)))

// ---------------- K1: coalesced LDS staging + scores + argmax + global histogram ----------------
__global__ __launch_bounds__(128) void score_kernel(const float* __restrict__ pred,
                                                    float* __restrict__ scores,
                                                    uint8_t* __restrict__ cls,
                                                    unsigned int* __restrict__ hist) {
  __shared__ __align__(16) float srow[SROWS * ROW];  // 21760 B
  const int tile = blockIdx.x;
  const int b = blockIdx.y;
  const int tid = threadIdx.x;
  const int lane = tid & 63;
  const int row0 = tile * SROWS;
  int nrows = NN - row0;
  if (nrows > SROWS) nrows = SROWS;
  const char* gsrc = (const char*)(pred + ((size_t)b * NN + row0) * ROW);
  const int nbytes = nrows * ROW * 4;
  for (int off = tid * 16; off < nbytes; off += 128 * 16) {
    __builtin_amdgcn_global_load_lds((AS1 void*)(gsrc + off),
                                     (AS3 void*)((char*)srow + (off - lane * 16)),
                                     16, 0, 0);
  }
  __builtin_amdgcn_s_waitcnt(0);
  __syncthreads();
  if (tid < nrows) {
    const int n = row0 + tid;
    const float* r = srow + tid * ROW;   // stride 85 dwords -> 2-way bank alias (free)
    float obj = r[4];
    float best = r[5];
    int bid = 0;
#pragma unroll
    for (int c = 1; c < NCLS; ++c) {
      float p = r[5 + c];
      if (p > best) { best = p; bid = c; }   // strict > keeps first max (tie rule)
    }
    float score = obj * best;
    bool valid = (obj > CONF) && (score > CONF);
    float sout = valid ? score : 0.0f;
    scores[(size_t)b * NN + n] = sout;
    cls[(size_t)b * NN + n] = (uint8_t)bid;
    if (valid) {
      unsigned int u = __float_as_uint(sout);        // in (0x3E800000, 0x3F800000)
      unsigned int bin = (u - (STH + 1u)) >> 12;
      if (bin > NBIN - 1) bin = NBIN - 1;
      atomicAdd(&hist[(size_t)b * NBIN + bin], 1u);
    }
  }
}

// ---------------- K2: per-batch suffix scan of hist -> gsoff, pivot P, total ----------------
// (gcnt zeroing moved to the single memset covering hist+gcnt)
__global__ __launch_bounds__(256) void scan_kernel(const unsigned int* __restrict__ hist,
                                                   unsigned int* __restrict__ gsoff,
                                                   int* __restrict__ gP,
                                                   int* __restrict__ gtot) {
  const int b = blockIdx.x;
  const int t = threadIdx.x;
  const int w = t >> 6, lane = t & 63;
  const unsigned int* h = hist + (size_t)b * NBIN;
  unsigned int loc[16];
  int ssum = 0;
#pragma unroll
  for (int k = 0; k < 16; ++k) {
    loc[k] = h[NBIN - 1 - (16 * t + k)];   // descending bins
    ssum += (int)loc[k];
  }
  // wave-level inclusive scan of per-thread sums
  int v = ssum;
  for (int o = 1; o < 64; o <<= 1) { int u = __shfl_up(v, o); if (lane >= o) v += u; }
  __shared__ int sw[4];
  __shared__ int sfound;
  if (t == 0) sfound = 0;
  if (lane == 63) sw[w] = v;
  __syncthreads();
  int wbase = 0;
  for (int i = 0; i < w; ++i) wbase += sw[i];
  const int total = sw[0] + sw[1] + sw[2] + sw[3];
  int run = wbase + v - ssum;   // exclusive suffix-sum at this thread's first bin
#pragma unroll
  for (int k = 0; k < 16; ++k) {
    int bin = NBIN - 1 - (16 * t + k);
    gsoff[(size_t)b * NBIN + bin] = (unsigned int)run;
    int c = (int)loc[k];
    if (run < TK && run + c >= TK) {   // unique bin satisfies this
      gP[b] = bin;
      gtot[b] = run + c;
      sfound = 1;
    }
    run += c;
  }
  __syncthreads();
  if (t == 0 && !sfound) { gP[b] = 0; gtot[b] = total; }  // < TK valid (never here)
}

// ---------------- K3: multi-block scatter to exact bin segments (global atomics) ----------------
__global__ __launch_bounds__(1024) void scatter_kernel(const float* __restrict__ scores,
                                                       const unsigned int* __restrict__ gsoff,
                                                       const int* __restrict__ gP,
                                                       unsigned int* __restrict__ gcnt,
                                                       unsigned long long* __restrict__ gskey) {
  const int b = blockIdx.y;
  const int n = blockIdx.x * 1024 + threadIdx.x;
  if (n >= NN) return;
  const unsigned int P = (unsigned int)gP[b];
  unsigned int u = __float_as_uint(scores[(size_t)b * NN + n]);
  if (u > STH) {
    unsigned int bin = (u - (STH + 1u)) >> 12;
    if (bin > NBIN - 1) bin = NBIN - 1;
    if (bin >= P) {
      unsigned int pos = gsoff[(size_t)b * NBIN + bin] +
                         atomicAdd(&gcnt[(size_t)b * NBIN + bin], 1u);
      if (pos < SORTN)
        gskey[(size_t)b * SORTN + pos] = ((unsigned long long)u << 32) | (unsigned int)(~n);
    }
  }
}

// ---------------- K4: wide rank-by-count emit, one thread per scatter position ----------------
__global__ __launch_bounds__(1024) void emit_kernel(const float* __restrict__ pred,
                                                    const uint8_t* __restrict__ cls,
                                                    const unsigned int* __restrict__ gsoff,
                                                    const unsigned int* __restrict__ gcnt,
                                                    const unsigned long long* __restrict__ gskey,
                                                    const int* __restrict__ gtot,
                                                    float* __restrict__ gtops,
                                                    fvec4* __restrict__ gbox,
                                                    int* __restrict__ gcls) {
  const int b = blockIdx.y;
  const int stride = gridDim.x * 1024;
  const int tot = gtot[b];
  const int used = tot < SORTN ? tot : SORTN;
  const int npos = tot < TK ? tot : TK;
  // pad job: fill [npos, TK) (no-op when tot >= TK)
  for (int ip = npos + blockIdx.x * 1024 + threadIdx.x; ip < TK; ip += stride) {
    gtops[(size_t)b * TK + ip] = 0.0f;
    gcls[(size_t)b * TK + ip] = 0xFFFF;
    fvec4 z; z[0] = 0.f; z[1] = 0.f; z[2] = 0.f; z[3] = 0.f;
    gbox[(size_t)b * TK + ip] = z;
  }
  for (int pp = blockIdx.x * 1024 + threadIdx.x; pp < used; pp += stride) {
    unsigned long long k = gskey[(size_t)b * SORTN + pp];
    unsigned int u = (unsigned int)(k >> 32);
    unsigned int bin = (u - (STH + 1u)) >> 12;
    if (bin > NBIN - 1) bin = NBIN - 1;
    int base = (int)gsoff[(size_t)b * NBIN + bin];
    int cnt = (int)gcnt[(size_t)b * NBIN + bin];
    if (base + cnt > used) cnt = used - base;   // safety
    const unsigned long long* seg = gskey + (size_t)b * SORTN + base;
    int rank = 0;
    for (int j = 0; j < cnt; ++j) rank += (seg[j] > k) ? 1 : 0;   // L2-resident, avg ~6
    int q = base + rank;                 // bijection over the segment (keys unique)
    if (q < npos) {
      int idx = (int)(~(unsigned int)k);
      gtops[(size_t)b * TK + q] = __uint_as_float(u);
      gcls[(size_t)b * TK + q] = (int)cls[(size_t)b * NN + idx];
      const float* rowp = pred + ((size_t)b * NN + idx) * ROW;
      float cx = rowp[0], cy = rowp[1], w2 = rowp[2], h2 = rowp[3];
      float hw = w2 * 0.5f, hh = h2 * 0.5f;
      fvec4 bb4;
      bb4[0] = cx - hw; bb4[1] = cy - hh; bb4[2] = cx + hw; bb4[3] = cy + hh;
      gbox[(size_t)b * TK + q] = bb4;
    }
  }
}

// ---------------- K5: greedy NMS, one wave per (batch, class) — member-staged, slim LDS ----
// LDS 38 KB -> ~10.2 KB: spos[TK] + skp[TK] + member boxes[MCAP]. Members with rank < 64
// additionally live in registers (suppress loop is pure shfl/VALU for m <= 64, the real case);
// rank in [64, MCAP) reads LDS; rank >= MCAP (never: m ~ Binomial(2048,1/80)) reads global gbox.
__global__ __launch_bounds__(64) void nms_kernel(const float* __restrict__ gtops,
                                                 const fvec4* __restrict__ gbox,
                                                 const int* __restrict__ gcls,
                                                 int* __restrict__ keep) {
  const int c = blockIdx.x;
  const int b = blockIdx.y;
  const int lane = threadIdx.x;
  __shared__ unsigned short spos[TK];                      // member -> global slot (4 KB)
  __shared__ float mx1[MCAP], my1[MCAP], mx2[MCAP], my2[MCAP];  // 4 KB
  __shared__ unsigned char skp[TK];                        // member keep flags (2 KB)

  int m = 0;
  for (int base = 0; base < TK; base += 64) {
    int j = base + lane;
    bool match = (gcls[(size_t)b * TK + j] == c);
    unsigned long long bal = __ballot(match);
    int mp = m + __popcll(bal & ((1ull << lane) - 1ull));
    if (match) {
      spos[mp] = (unsigned short)j;
      skp[mp] = (gtops[(size_t)b * TK + j] > 0.0f) ? 1 : 0;
      if (mp < MCAP) {
        fvec4 bx = gbox[(size_t)b * TK + j];
        mx1[mp] = bx[0]; my1[mp] = bx[1]; mx2[mp] = bx[2]; my2[mp] = bx[3];
      }
    }
    m += (int)__popcll(bal);
  }
  __syncthreads();

  // chunk-0 member box in registers (lane < 64 <= MCAP always staged)
  float b0x1 = 0.f, b0y1 = 0.f, b0x2 = 0.f, b0y2 = 0.f;
  if (lane < m) { b0x1 = mx1[lane]; b0y1 = my1[lane]; b0x2 = mx2[lane]; b0y2 = my2[lane]; }
  __syncthreads();

  for (int i = 0; i < m; ++i) {
    if (!skp[i]) continue;            // uniform broadcast read
    float ax1, ay1, ax2, ay2;
    if (i < 64) {
      ax1 = __shfl(b0x1, i); ay1 = __shfl(b0y1, i);
      ax2 = __shfl(b0x2, i); ay2 = __shfl(b0y2, i);
    } else if (i < MCAP) {
      ax1 = mx1[i]; ay1 = my1[i]; ax2 = mx2[i]; ay2 = my2[i];
    } else {                          // never in practice
      fvec4 bx = gbox[(size_t)b * TK + spos[i]];
      ax1 = bx[0]; ay1 = bx[1]; ax2 = bx[2]; ay2 = bx[3];
    }
    float aarea = (ax2 - ax1) * (ay2 - ay1);
    for (int q = 0; q * 64 < m; ++q) {
      int j = q * 64 + lane;          // each lane owns j == lane (mod 64): exclusive skp writes
      if (j > i && j < m && skp[j]) {
        float jx1, jy1, jx2, jy2;
        if (q == 0) { jx1 = b0x1; jy1 = b0y1; jx2 = b0x2; jy2 = b0y2; }
        else if (j < MCAP) { jx1 = mx1[j]; jy1 = my1[j]; jx2 = mx2[j]; jy2 = my2[j]; }
        else { fvec4 bx = gbox[(size_t)b * TK + spos[j]];
               jx1 = bx[0]; jy1 = bx[1]; jx2 = bx[2]; jy2 = bx[3]; }
        float ltx = fmaxf(ax1, jx1), lty = fmaxf(ay1, jy1);
        float rbx = fminf(ax2, jx2), rby = fminf(ay2, jy2);
        float iw = fmaxf(rbx - ltx, 0.0f);
        float ih = fmaxf(rby - lty, 0.0f);
        float inter = iw * ih;
        float barea = (jx2 - jx1) * (jy2 - jy1);
        float iou = inter / (aarea + barea - inter + 1e-7f);
        if (iou > IOUT) skp[j] = 0;
      }
    }
  }
  __syncthreads();

  for (int i = lane; i < m; i += 64) {
    keep[(size_t)b * TK + spos[i]] = skp[i];
  }
}

// ---------------- K6: compact first 1000 kept + padding — R0-proven structure ----------------
__global__ __launch_bounds__(256) void out_kernel(const float* __restrict__ gtops,
                                                  const fvec4* __restrict__ gbox,
                                                  const int* __restrict__ gcls,
                                                  const int* __restrict__ keep,
                                                  const int* __restrict__ gtot,
                                                  float* __restrict__ out) {
  int b = blockIdx.x;
  int t = threadIdx.x;
  __shared__ int scnt[256];
  int npos = gtot[b];
  if (npos > TK) npos = TK;
  const int CH = TK / 256;  // 8
  int base = t * CH;
  int kp[CH];
  int cnt = 0;
  for (int k = 0; k < CH; ++k) {
    int j = base + k;
    kp[k] = (j < npos) ? keep[(size_t)b * TK + j] : 0;
    cnt += kp[k];
  }
  scnt[t] = cnt;
  __syncthreads();
  for (int off = 1; off < 256; off <<= 1) {
    int v = (t >= off) ? scnt[t - off] : 0;
    __syncthreads();
    scnt[t] += v;
    __syncthreads();
  }
  int r = scnt[t] - cnt;
  int K = scnt[255];
  for (int k = 0; k < CH; ++k) {
    if (kp[k]) {
      if (r < MAXDET) {
        int j = base + k;
        float* o = out + ((size_t)b * MAXDET + r) * 6;
        fvec4 bx = gbox[(size_t)b * TK + j];
        o[0] = bx[0]; o[1] = bx[1]; o[2] = bx[2]; o[3] = bx[3];
        o[4] = gtops[(size_t)b * TK + j];
        o[5] = (float)gcls[(size_t)b * TK + j];
      }
      ++r;
    }
  }
  int Kc = K < MAXDET ? K : MAXDET;
  for (int r2 = Kc + t; r2 < MAXDET; r2 += 256) {
    float* o = out + ((size_t)b * MAXDET + r2) * 6;
    o[0] = 0.0f; o[1] = 0.0f; o[2] = 0.0f; o[3] = 0.0f; o[4] = 0.0f; o[5] = -1.0f;
  }
}

extern "C" void kernel_launch(void* const* d_in, const int* in_sizes, int n_in,
                              void* d_out, int out_size, void* d_ws, size_t ws_size,
                              hipStream_t stream) {
  const float* pred = (const float*)d_in[0];
  float* out = (float*)d_out;

  char* ws = (char*)d_ws;
  size_t off = 0;
  float*              scores = (float*)(ws + off);              off += (size_t)BB * NN * 4;
  uint8_t*            cls    = (uint8_t*)(ws + off);            off += (size_t)BB * NN;
  off = (off + 255) & ~(size_t)255;
  unsigned int*       hist   = (unsigned int*)(ws + off);       off += (size_t)BB * NBIN * 4;
  unsigned int*       gcnt   = (unsigned int*)(ws + off);       off += (size_t)BB * NBIN * 4;
  unsigned int*       gsoff  = (unsigned int*)(ws + off);       off += (size_t)BB * NBIN * 4;
  unsigned long long* gskey  = (unsigned long long*)(ws + off); off += (size_t)BB * SORTN * 8;
  float*              gtops  = (float*)(ws + off);              off += (size_t)BB * TK * 4;
  fvec4*              gbox   = (fvec4*)(ws + off);              off += (size_t)BB * TK * 16;
  int*                gcls   = (int*)(ws + off);                off += (size_t)BB * TK * 4;
  int*                keep   = (int*)(ws + off);                off += (size_t)BB * TK * 4;
  int*                gP     = (int*)(ws + off);                off += (size_t)BB * 4;
  int*                gtot   = (int*)(ws + off);                off += (size_t)BB * 4;
  (void)ws_size; (void)in_sizes; (void)n_in; (void)out_size;

  // one memset clears hist AND gcnt (adjacent)
  hipMemsetAsync(hist, 0, (size_t)BB * NBIN * 4 * 2, stream);
  score_kernel<<<dim3((NN + SROWS - 1) / SROWS, BB), 128, 0, stream>>>(pred, scores, cls, hist);
  scan_kernel<<<BB, 256, 0, stream>>>(hist, gsoff, gP, gtot);
  scatter_kernel<<<dim3((NN + 1023) / 1024, BB), 1024, 0, stream>>>(scores, gsoff, gP, gcnt, gskey);
  emit_kernel<<<dim3(SORTN / 1024, BB), 1024, 0, stream>>>(pred, cls, gsoff, gcnt, gskey, gtot,
                                                           gtops, gbox, gcls);
  nms_kernel<<<dim3(NCLS, BB), 64, 0, stream>>>(gtops, gbox, gcls, keep);
  out_kernel<<<BB, 256, 0, stream>>>(gtops, gbox, gcls, keep, gtot, out);
}

// Round 10
// 243.468 us; speedup vs baseline: 1.1632x; 1.0158x over previous
//
#include <hip/hip_runtime.h>
#include <stdint.h>

#pragma clang fp contract(off)

#define BB 16
#define NN 25200
#define ROW 85
#define NCLS 80
#define TK 2048
#define SORTN 4096
#define NBIN 4096
#define MAXDET 1000
#define CONF 0.25f
#define IOUT 0.45f
#define SROWS 64
#define STH 0x3E800000u
#define MCAP 256

typedef float fvec4 __attribute__((ext_vector_type(4)));

#define AS1 __attribute__((address_space(1)))
#define AS3 __attribute__((address_space(3)))

// ---------------- K1: coalesced LDS staging + scores + argmax + global histogram ----------------
__global__ __launch_bounds__(128) void score_kernel(const float* __restrict__ pred,
                                                    float* __restrict__ scores,
                                                    uint8_t* __restrict__ cls,
                                                    unsigned int* __restrict__ hist) {
  __shared__ __align__(16) float srow[SROWS * ROW];  // 21760 B
  const int tile = blockIdx.x;
  const int b = blockIdx.y;
  const int tid = threadIdx.x;
  const int lane = tid & 63;
  const int row0 = tile * SROWS;
  int nrows = NN - row0;
  if (nrows > SROWS) nrows = SROWS;
  const char* gsrc = (const char*)(pred + ((size_t)b * NN + row0) * ROW);
  const int nbytes = nrows * ROW * 4;
  for (int off = tid * 16; off < nbytes; off += 128 * 16) {
    __builtin_amdgcn_global_load_lds((AS1 void*)(gsrc + off),
                                     (AS3 void*)((char*)srow + (off - lane * 16)),
                                     16, 0, 0);
  }
  __builtin_amdgcn_s_waitcnt(0);
  __syncthreads();
  if (tid < nrows) {
    const int n = row0 + tid;
    const float* r = srow + tid * ROW;   // stride 85 dwords -> 2-way bank alias (free)
    float obj = r[4];
    float best = r[5];
    int bid = 0;
#pragma unroll
    for (int c = 1; c < NCLS; ++c) {
      float p = r[5 + c];
      if (p > best) { best = p; bid = c; }   // strict > keeps first max (tie rule)
    }
    float score = obj * best;
    bool valid = (obj > CONF) && (score > CONF);
    float sout = valid ? score : 0.0f;
    scores[(size_t)b * NN + n] = sout;
    cls[(size_t)b * NN + n] = (uint8_t)bid;
    if (valid) {
      unsigned int u = __float_as_uint(sout);        // in (0x3E800000, 0x3F800000)
      unsigned int bin = (u - (STH + 1u)) >> 12;
      if (bin > NBIN - 1) bin = NBIN - 1;
      atomicAdd(&hist[(size_t)b * NBIN + bin], 1u);
    }
  }
}

// ---- 1024-thread per-block suffix scan over descending bins (R6 phase-2, proven) ----
// Fills soff[NBIN] (exclusive count of strictly-higher bins), *sPP = pivot, *sTT = total above+at pivot.
__device__ __forceinline__ void suffix_scan_1024(const unsigned int* __restrict__ h,
                                                 unsigned int* soff, int* swsum,
                                                 int* sPP, int* sTT,
                                                 int t, int w, int lane) {
  int loc[4];
  int ssum = 0;
#pragma unroll
  for (int k = 0; k < 4; ++k) {
    loc[k] = (int)h[NBIN - 1 - (4 * t + k)];
    ssum += loc[k];
  }
  int v = ssum;
  for (int o = 1; o < 64; o <<= 1) { int uu = __shfl_up(v, o); if (lane >= o) v += uu; }
  if (lane == 63) swsum[w] = v;
  if (t == 0) *sPP = -1;
  __syncthreads();
  if (w == 0) {
    int x = (lane < 16) ? swsum[lane] : 0;
    for (int o = 1; o < 16; o <<= 1) { int uu = __shfl_up(x, o); if (lane >= o) x += uu; }
    if (lane < 16) swsum[lane] = x;   // inclusive wave sums
  }
  __syncthreads();
  const int total = swsum[15];
  int run = (w ? swsum[w - 1] : 0) + (v - ssum);
#pragma unroll
  for (int k = 0; k < 4; ++k) {
    int bin = NBIN - 1 - (4 * t + k);
    soff[bin] = (unsigned int)run;
    if (run < TK && run + loc[k] >= TK) { *sPP = bin; *sTT = run + loc[k]; }  // unique bin
    run += loc[k];
  }
  __syncthreads();
  if (t == 0 && *sPP < 0) { *sPP = 0; *sTT = total; }  // total < TK (never with this data)
  __syncthreads();
}

// ---------------- K2: scatter to exact bin segments (per-block recomputed scan) ----------------
__global__ __launch_bounds__(1024) void scatter_kernel(const float* __restrict__ scores,
                                                       const unsigned int* __restrict__ hist,
                                                       unsigned int* __restrict__ gcnt,
                                                       unsigned long long* __restrict__ gskey) {
  const int b = blockIdx.y;
  const int t = threadIdx.x;
  const int w = t >> 6, lane = t & 63;
  __shared__ unsigned int soff[NBIN];   // 16 KB
  __shared__ int swsum[16];
  __shared__ int sP, sT;
  suffix_scan_1024(hist + (size_t)b * NBIN, soff, swsum, &sP, &sT, t, w, lane);
  const int P = sP;
  const int n = blockIdx.x * 1024 + t;
  if (n >= NN) return;
  unsigned int u = __float_as_uint(scores[(size_t)b * NN + n]);
  if (u > STH) {
    unsigned int bin = (u - (STH + 1u)) >> 12;
    if (bin > NBIN - 1) bin = NBIN - 1;
    if ((int)bin >= P) {
      unsigned int pos = soff[bin] + atomicAdd(&gcnt[(size_t)b * NBIN + bin], 1u);
      if (pos < SORTN)
        gskey[(size_t)b * SORTN + pos] = ((unsigned long long)u << 32) | (unsigned int)(~n);
    }
  }
}

// ---------------- K3: wide rank-by-count emit (per-block recomputed scan) ----------------
// Also zeroes keep[] for pad slots -> downstream needs no gtot guard (full keep coverage:
// slot < npos has a real class -> some nms block writes it; slot >= npos -> pad writes 0).
__global__ __launch_bounds__(1024) void emit_kernel(const float* __restrict__ pred,
                                                    const uint8_t* __restrict__ cls,
                                                    const unsigned int* __restrict__ hist,
                                                    const unsigned long long* __restrict__ gskey,
                                                    float* __restrict__ gtops,
                                                    fvec4* __restrict__ gbox,
                                                    int* __restrict__ gcls,
                                                    int* __restrict__ keep) {
  const int b = blockIdx.y;
  const int t = threadIdx.x;
  const int w = t >> 6, lane = t & 63;
  __shared__ unsigned int soff[NBIN];   // 16 KB
  __shared__ int swsum[16];
  __shared__ int sP, sT;
  const unsigned int* h = hist + (size_t)b * NBIN;
  suffix_scan_1024(h, soff, swsum, &sP, &sT, t, w, lane);
  const int tot = sT;
  const int used = tot < SORTN ? tot : SORTN;
  const int npos = tot < TK ? tot : TK;
  const int pp = blockIdx.x * 1024 + t;   // [0, SORTN)
  // pad job: fill [npos, TK) (no-op when tot >= TK)
  int ip = npos + pp;
  if (ip < TK) {
    gtops[(size_t)b * TK + ip] = 0.0f;
    gcls[(size_t)b * TK + ip] = 0xFFFF;
    keep[(size_t)b * TK + ip] = 0;
    fvec4 z; z[0] = 0.f; z[1] = 0.f; z[2] = 0.f; z[3] = 0.f;
    gbox[(size_t)b * TK + ip] = z;
  }
  if (pp < used) {
    unsigned long long k = gskey[(size_t)b * SORTN + pp];
    unsigned int u = (unsigned int)(k >> 32);
    unsigned int bin = (u - (STH + 1u)) >> 12;
    if (bin > NBIN - 1) bin = NBIN - 1;
    int base = (int)soff[bin];
    int cnt = (int)h[bin];               // scattered count == hist count (no drops: tot <= SORTN)
    if (base + cnt > used) cnt = used - base;   // safety
    const unsigned long long* seg = gskey + (size_t)b * SORTN + base;
    int rank = 0;
    for (int j = 0; j < cnt; ++j) rank += (seg[j] > k) ? 1 : 0;   // L2-resident, avg ~6
    int q = base + rank;                 // bijection over the segment (keys unique)
    if (q < npos) {
      int idx = (int)(~(unsigned int)k);
      gtops[(size_t)b * TK + q] = __uint_as_float(u);
      gcls[(size_t)b * TK + q] = (int)cls[(size_t)b * NN + idx];
      const float* rowp = pred + ((size_t)b * NN + idx) * ROW;
      float cx = rowp[0], cy = rowp[1], w2 = rowp[2], h2 = rowp[3];
      float hw = w2 * 0.5f, hh = h2 * 0.5f;
      fvec4 bb4;
      bb4[0] = cx - hw; bb4[1] = cy - hh; bb4[2] = cx + hw; bb4[3] = cy + hh;
      gbox[(size_t)b * TK + q] = bb4;
    }
  }
}

// ---------------- K4: greedy NMS, one wave per (batch, class) — member-staged, slim LDS ----
__global__ __launch_bounds__(64) void nms_kernel(const float* __restrict__ gtops,
                                                 const fvec4* __restrict__ gbox,
                                                 const int* __restrict__ gcls,
                                                 int* __restrict__ keep) {
  const int c = blockIdx.x;
  const int b = blockIdx.y;
  const int lane = threadIdx.x;
  __shared__ unsigned short spos[TK];                      // member -> global slot (4 KB)
  __shared__ float mx1[MCAP], my1[MCAP], mx2[MCAP], my2[MCAP];  // 4 KB
  __shared__ unsigned char skp[TK];                        // member keep flags (2 KB)

  int m = 0;
#pragma unroll 4
  for (int base = 0; base < TK; base += 64) {
    int j = base + lane;
    bool match = (gcls[(size_t)b * TK + j] == c);
    unsigned long long bal = __ballot(match);
    int mp = m + __popcll(bal & ((1ull << lane) - 1ull));
    if (match) {
      spos[mp] = (unsigned short)j;
      skp[mp] = (gtops[(size_t)b * TK + j] > 0.0f) ? 1 : 0;
      if (mp < MCAP) {
        fvec4 bx = gbox[(size_t)b * TK + j];
        mx1[mp] = bx[0]; my1[mp] = bx[1]; mx2[mp] = bx[2]; my2[mp] = bx[3];
      }
    }
    m += (int)__popcll(bal);
  }
  __syncthreads();

  // chunk-0 member box in registers (lane < 64 <= MCAP always staged)
  float b0x1 = 0.f, b0y1 = 0.f, b0x2 = 0.f, b0y2 = 0.f;
  if (lane < m) { b0x1 = mx1[lane]; b0y1 = my1[lane]; b0x2 = mx2[lane]; b0y2 = my2[lane]; }
  __syncthreads();

  for (int i = 0; i < m; ++i) {
    if (!skp[i]) continue;            // uniform broadcast read
    float ax1, ay1, ax2, ay2;
    if (i < 64) {
      ax1 = __shfl(b0x1, i); ay1 = __shfl(b0y1, i);
      ax2 = __shfl(b0x2, i); ay2 = __shfl(b0y2, i);
    } else if (i < MCAP) {
      ax1 = mx1[i]; ay1 = my1[i]; ax2 = mx2[i]; ay2 = my2[i];
    } else {                          // never in practice
      fvec4 bx = gbox[(size_t)b * TK + spos[i]];
      ax1 = bx[0]; ay1 = bx[1]; ax2 = bx[2]; ay2 = bx[3];
    }
    float aarea = (ax2 - ax1) * (ay2 - ay1);
    for (int q = 0; q * 64 < m; ++q) {
      int j = q * 64 + lane;          // each lane owns j == lane (mod 64): exclusive skp writes
      if (j > i && j < m && skp[j]) {
        float jx1, jy1, jx2, jy2;
        if (q == 0) { jx1 = b0x1; jy1 = b0y1; jx2 = b0x2; jy2 = b0y2; }
        else if (j < MCAP) { jx1 = mx1[j]; jy1 = my1[j]; jx2 = mx2[j]; jy2 = my2[j]; }
        else { fvec4 bx = gbox[(size_t)b * TK + spos[j]];
               jx1 = bx[0]; jy1 = bx[1]; jx2 = bx[2]; jy2 = bx[3]; }
        float ltx = fmaxf(ax1, jx1), lty = fmaxf(ay1, jy1);
        float rbx = fminf(ax2, jx2), rby = fminf(ay2, jy2);
        float iw = fmaxf(rbx - ltx, 0.0f);
        float ih = fmaxf(rby - lty, 0.0f);
        float inter = iw * ih;
        float barea = (jx2 - jx1) * (jy2 - jy1);
        float iou = inter / (aarea + barea - inter + 1e-7f);
        if (iou > IOUT) skp[j] = 0;
      }
    }
  }
  __syncthreads();

  for (int i = lane; i < m; i += 64) {
    keep[(size_t)b * TK + spos[i]] = skp[i];
  }
}

// ---------------- K5: compact first 1000 kept + padding (shfl scan; keep fully covered) ----------------
__global__ __launch_bounds__(256) void out_kernel(const float* __restrict__ gtops,
                                                  const fvec4* __restrict__ gbox,
                                                  const int* __restrict__ gcls,
                                                  const int* __restrict__ keep,
                                                  float* __restrict__ out) {
  int b = blockIdx.x;
  int t = threadIdx.x;
  int w = t >> 6, lane = t & 63;
  __shared__ int sw4[4];
  const int CH = TK / 256;  // 8
  int base = t * CH;
  int kp[CH];
  int cnt = 0;
  for (int k = 0; k < CH; ++k) {
    kp[k] = keep[(size_t)b * TK + base + k];   // pad slots hold 0 (written by emit)
    cnt += kp[k];
  }
  int v = cnt;
  for (int o = 1; o < 64; o <<= 1) { int u = __shfl_up(v, o); if (lane >= o) v += u; }
  if (lane == 63) sw4[w] = v;
  __syncthreads();
  int wbase = 0;
  for (int i = 0; i < w; ++i) wbase += sw4[i];
  int K = sw4[0] + sw4[1] + sw4[2] + sw4[3];
  int r = wbase + v - cnt;
  for (int k = 0; k < CH; ++k) {
    if (kp[k]) {
      if (r < MAXDET) {
        int j = base + k;
        float* o = out + ((size_t)b * MAXDET + r) * 6;
        fvec4 bx = gbox[(size_t)b * TK + j];
        o[0] = bx[0]; o[1] = bx[1]; o[2] = bx[2]; o[3] = bx[3];
        o[4] = gtops[(size_t)b * TK + j];
        o[5] = (float)gcls[(size_t)b * TK + j];
      }
      ++r;
    }
  }
  int Kc = K < MAXDET ? K : MAXDET;
  for (int r2 = Kc + t; r2 < MAXDET; r2 += 256) {
    float* o = out + ((size_t)b * MAXDET + r2) * 6;
    o[0] = 0.0f; o[1] = 0.0f; o[2] = 0.0f; o[3] = 0.0f; o[4] = 0.0f; o[5] = -1.0f;
  }
}

extern "C" void kernel_launch(void* const* d_in, const int* in_sizes, int n_in,
                              void* d_out, int out_size, void* d_ws, size_t ws_size,
                              hipStream_t stream) {
  const float* pred = (const float*)d_in[0];
  float* out = (float*)d_out;

  char* ws = (char*)d_ws;
  size_t off = 0;
  float*              scores = (float*)(ws + off);              off += (size_t)BB * NN * 4;
  uint8_t*            cls    = (uint8_t*)(ws + off);            off += (size_t)BB * NN;
  off = (off + 255) & ~(size_t)255;
  unsigned int*       hist   = (unsigned int*)(ws + off);       off += (size_t)BB * NBIN * 4;
  unsigned int*       gcnt   = (unsigned int*)(ws + off);       off += (size_t)BB * NBIN * 4;
  unsigned long long* gskey  = (unsigned long long*)(ws + off); off += (size_t)BB * SORTN * 8;
  float*              gtops  = (float*)(ws + off);              off += (size_t)BB * TK * 4;
  fvec4*              gbox   = (fvec4*)(ws + off);              off += (size_t)BB * TK * 16;
  int*                gcls   = (int*)(ws + off);                off += (size_t)BB * TK * 4;
  int*                keep   = (int*)(ws + off);                off += (size_t)BB * TK * 4;
  (void)ws_size; (void)in_sizes; (void)n_in; (void)out_size;

  // one memset clears hist AND gcnt (adjacent)
  hipMemsetAsync(hist, 0, (size_t)BB * NBIN * 4 * 2, stream);
  score_kernel<<<dim3((NN + SROWS - 1) / SROWS, BB), 128, 0, stream>>>(pred, scores, cls, hist);
  scatter_kernel<<<dim3((NN + 1023) / 1024, BB), 1024, 0, stream>>>(scores, hist, gcnt, gskey);
  emit_kernel<<<dim3(SORTN / 1024, BB), 1024, 0, stream>>>(pred, cls, hist, gskey,
                                                           gtops, gbox, gcls, keep);
  nms_kernel<<<dim3(NCLS, BB), 64, 0, stream>>>(gtops, gbox, gcls, keep);
  out_kernel<<<BB, 256, 0, stream>>>(gtops, gbox, gcls, keep, out);
}